// Round 10
// baseline (340.375 us; speedup 1.0000x reference)
//
#include <hip/hip_runtime.h>
#include <math.h>

#define BB 256
#define SS 30
#define CC 62
#define LL 169
#define OG 64
#define OH 64
#define KK1 64
#define KK2 32
#define KK3 14
#define FLEN 108     // 64+32+14-2

typedef __attribute__((ext_vector_type(8))) short s16x8;
typedef __attribute__((ext_vector_type(4))) float f32x4;

__device__ __forceinline__ unsigned short f2bf(float f) {
    unsigned u = __float_as_uint(f);
    u += 0x7fffu + ((u >> 16) & 1u);        // RTNE
    return (unsigned short)(u >> 16);
}
__device__ __forceinline__ float bflo(unsigned v) { return __uint_as_float(v << 16); }
__device__ __forceinline__ float bfhi(unsigned v) { return __uint_as_float(v & 0xffff0000u); }

// direct global->LDS DMA, 4B per lane (dest = wave-uniform base + lane*4)
__device__ __forceinline__ void gload_lds4(const void* g, void* l) {
    __builtin_amdgcn_global_load_lds(
        (const __attribute__((address_space(1))) void*)g,
        (__attribute__((address_space(3))) void*)l, 4, 0, 0);
}

// ---------------- setup stage 1 (1 block): weights prep + Bm ----------------
__global__ __launch_bounds__(1024) void k_setup1(
        const float* __restrict__ dw1, const float* __restrict__ dw1b,
        const float* __restrict__ pw1, const float* __restrict__ pw1b,
        const float* __restrict__ dw2, const float* __restrict__ dw2b,
        const float* __restrict__ pw2, const float* __restrict__ pw2b,
        const float* __restrict__ dw3, const float* __restrict__ dw3b,
        const float* __restrict__ pw3, const float* __restrict__ pw3b,
        const float* __restrict__ Wr, const float* __restrict__ Wrb, const float* __restrict__ br,
        const float* __restrict__ Wu, const float* __restrict__ Wub, const float* __restrict__ bu,
        const float* __restrict__ Wc, const float* __restrict__ Wcb, const float* __restrict__ bc,
        float* __restrict__ Bmg, float* __restrict__ WtAll,
        float* __restrict__ bias192, float* __restrict__ beff) {
    __shared__ float g23[CC * KK3];
    __shared__ float Am[CC * 45];
    __shared__ float by2[CC], vals[CC];
    int tid = threadIdx.x;

    for (int idx = tid; idx < OG * 192; idx += 1024) {
        int i = idx / 192, q = idx - i * 192;
        int gate = q >> 6, f = q & 63;
        const float* W = gate == 0 ? Wr : (gate == 1 ? Wu : Wc);
        WtAll[idx] = W[f * (OG + OH) + i];
    }
    if (tid < 192) {
        int gate = tid >> 6, f = tid & 63;
        const float* Wb = gate == 0 ? Wrb : (gate == 1 ? Wub : Wcb);
        const float* bb = gate == 0 ? br  : (gate == 1 ? bu  : bc);
        bias192[tid] = Wb[f] + bb[f];
    }
    for (int idx = tid; idx < CC * KK3; idx += 1024) {
        int c1 = idx / KK3, k3 = idx - c1 * KK3;
        float s = 0.f;
        for (int c2 = 0; c2 < CC; ++c2)
            s += pw3[61 * CC + c2] * pw2[c2 * CC + c1] * dw3[c2 * KK3 + k3];
        g23[idx] = s;
    }
    if (tid < CC) {
        int c1 = tid;
        float bz1 = pw1b[c1];
        for (int c0 = 0; c0 < CC; ++c0) bz1 += pw1[c1 * CC + c0] * dw1b[c0];
        float s2 = 0.f;
        for (int k = 0; k < KK2; ++k) s2 += dw2[c1 * KK2 + k];
        by2[c1] = dw2b[c1] + bz1 * s2;
    }
    __syncthreads();
    if (tid < CC) {
        int c2 = tid;
        float bz2 = pw2b[c2];
        for (int c1 = 0; c1 < CC; ++c1) bz2 += pw2[c2 * CC + c1] * by2[c1];
        float s3 = 0.f;
        for (int k = 0; k < KK3; ++k) s3 += dw3[c2 * KK3 + k];
        vals[c2] = pw3[61 * CC + c2] * (dw3b[c2] + bz2 * s3);
    }
    for (int idx = tid; idx < CC * 45; idx += 1024) {
        int c1 = idx / 45, m = idx - c1 * 45;
        int k2lo = max(0, m - (KK3 - 1));
        int k2hi = min(KK2 - 1, m);
        float s = 0.f;
        for (int k2 = k2lo; k2 <= k2hi; ++k2)
            s += dw2[c1 * KK2 + k2] * g23[c1 * KK3 + (m - k2)];
        Am[idx] = s;
    }
    __syncthreads();
    if (tid == 0) {
        float s = pw3b[61];
        for (int c2 = 0; c2 < CC; ++c2) s += vals[c2];
        *beff = s;
    }
    for (int idx = tid; idx < CC * 45; idx += 1024) {
        int c0 = idx / 45, m = idx - c0 * 45;
        float s = 0.f;
        for (int c1 = 0; c1 < CC; ++c1) s += pw1[c1 * CC + c0] * Am[c1 * 45 + m];
        Bmg[idx] = s;
    }
}

// ---------------- setup stage 2 (64 blocks): Ftb[o][c0] ----------------
__global__ __launch_bounds__(128) void k_setupF(
        const float* __restrict__ Bmg, const float* __restrict__ dw1,
        unsigned short* __restrict__ Ftb) {
    __shared__ float Bl[45];
    int c0 = blockIdx.x;
    int o = threadIdx.x;
    if (c0 < CC && o < 45) Bl[o] = Bmg[c0 * 45 + o];
    __syncthreads();
    if (o >= 112) return;
    float s = 0.f;
    if (c0 < CC && o < FLEN) {
        int mlo = max(0, o - (KK1 - 1));
        int mhi = min(44, o);
        for (int m = mlo; m <= mhi; ++m)
            s += Bl[m] * dw1[c0 * KK1 + (o - m)];
    }
    Ftb[o * 64 + c0] = f2bf(s);
}

// ---------------- main: one block per (b,t) -> adjt -> wx ----------------
__global__ __launch_bounds__(256, 2) void k_main(
        const float* __restrict__ x, const float* __restrict__ adj,
        const unsigned short* __restrict__ Ftb, const float* __restrict__ beff_p,
        float* __restrict__ wxb) {
    __shared__ __align__(16) unsigned xf32[10478];          // 41912 B linear [c][l] f32 tile
    __shared__ __align__(16) unsigned short xT[176 * 64];   // 22528 B swizzled [l][c] bf16
    __shared__ float dacc[4][64];
    __shared__ float adjt[CC];
    int bt = blockIdx.x;
    int tid = threadIdx.x;
    int lane = tid & 63, wid = tid >> 6;
    const float* xg = x + (size_t)bt * (CC * LL);
    unsigned* xTu = (unsigned*)xT;

    // 1) DMA the whole tile into LDS: 41 x (256 dwords); no VGPR round-trip,
    //    all loads stay in the vm queue -> HBM-saturating depth.
    #pragma unroll
    for (int it = 0; it < 41; ++it) {
        int di = it * 256 + tid;
        if (di < 10478)
            gload_lds4((const char*)xg + (size_t)di * 4,
                       (char*)xf32 + it * 1024 + wid * 256);
    }
    // aux loads overlap the DMA drain
    float be = *beff_p;
    float arow = 0.f;
    if (tid < CC) arow = adj[61 * CC + tid];
    int col = lane & 15, rb4 = lane >> 4;
    const unsigned short* ap0 = Ftb + ((wid * 16 + col) * 64 + rb4 * 8);
    s16x8 pa0 = *(const s16x8*)ap0;
    s16x8 pa1 = *(const s16x8*)(ap0 + 32);
    // zero dacc + xT pads while DMA flies
    ((float*)dacc)[tid] = 0.f;
    for (int i = tid; i < 169; i += 256) xTu[(i * 32 + 31) ^ ((i & 7) << 2)] = 0;
    for (int i = tid; i < 224; i += 256) {
        int r = 169 + (i >> 5), d2 = i & 31;
        xTu[(r * 32 + d2) ^ ((r & 7) << 2)] = 0;
    }
    __syncthreads();    // vmcnt(0) drain + barrier

    // 2) transpose + f32->bf16 convert into swizzled xT
    //    lanes vary cp -> writes spread over 31 banks (free); reads 2-way (free)
    for (int idx = tid; idx < 31 * 169; idx += 256) {
        int l = idx / 31, cp = idx - l * 31;
        unsigned lo = xf32[(2 * cp) * 169 + l];
        unsigned hi = xf32[(2 * cp + 1) * 169 + l];
        unsigned v = (unsigned)f2bf(__uint_as_float(lo))
                   | ((unsigned)f2bf(__uint_as_float(hi)) << 16);
        xTu[(l * 32 + cp) ^ ((l & 7) << 2)] = v;
    }
    __syncthreads();

    // 3) MFMA band: wave wid handles mt in {wid, wid+4}; zacc[d] accumulates across mt
    f32x4 zacc[5];
    #pragma unroll
    for (int d = 0; d < 5; ++d) zacc[d] = (f32x4){0.f, 0.f, 0.f, 0.f};
    int kb = rb4 * 16;
    int xr = (lane & 7) << 4;
    #pragma unroll
    for (int h = 0; h < 2; ++h) {
        int mt = wid + 4 * h;
        if (mt < 7) {
            s16x8 a0, a1;
            if (h == 0) { a0 = pa0; a1 = pa1; }
            else {
                const unsigned short* ap = Ftb + ((mt * 16 + col) * 64 + rb4 * 8);
                a0 = *(const s16x8*)ap;
                a1 = *(const s16x8*)(ap + 32);
            }
            #pragma unroll
            for (int d = 0; d < 5; ++d) {
                int nt = mt + d;
                int bbyte = ((nt * 16 + col) * 128 + kb) ^ xr;
                s16x8 b0 = *(const s16x8*)((const char*)xT + bbyte);
                s16x8 b1 = *(const s16x8*)((const char*)xT + bbyte + 64);
                zacc[d] = __builtin_amdgcn_mfma_f32_16x16x32_bf16(a0, b0, zacc[d], 0, 0, 0);
                zacc[d] = __builtin_amdgcn_mfma_f32_16x16x32_bf16(a1, b1, zacc[d], 0, 0, 0);
            }
        }
    }
    int jc = col - rb4 * 4;
    #pragma unroll
    for (int d = 0; d < 5; ++d) {
        #pragma unroll
        for (int r = 0; r < 4; ++r) {
            int j = 16 * d + jc - r;
            if ((unsigned)j < 62u) atomicAdd(&dacc[rb4][j], zacc[d][r]);
        }
    }
    __syncthreads();

    // 4) sigmoid
    if (tid < CC) {
        float dv = dacc[0][tid] + dacc[1][tid] + dacc[2][tid] + dacc[3][tid];
        adjt[tid] = 1.f / (1.f + __expf(-(dv + be + arow)));
    }
    __syncthreads();

    // 5) wx from the f32 tile (conflict-free reads), rows padded to 176
    if (tid < 176) {
        float s = 0.f;
        if (tid < LL) {
            #pragma unroll 2
            for (int j = 0; j < CC; ++j)
                s += adjt[j] * __uint_as_float(xf32[j * LL + tid]);
        }
        wxb[(size_t)bt * 176 + tid] = s;
    }
}

// ---------------- fused G + gates: 8 bt per block ----------------
__global__ __launch_bounds__(256) void k_gg(
        const float* __restrict__ wxb, const float* __restrict__ gcnw,
        const float* __restrict__ gcnb, const float* __restrict__ WtAll,
        const float* __restrict__ bias192, float* __restrict__ gates) {
    __shared__ float wxl[8 * 176];
    __shared__ float Gl[8 * 64];
    int bt0 = blockIdx.x * 8;
    int tid = threadIdx.x;
    const float* src = wxb + (size_t)bt0 * 176;
    for (int i = tid; i < 8 * 176; i += 256) wxl[i] = src[i];
    __syncthreads();
    #pragma unroll
    for (int rep = 0; rep < 2; ++rep) {
        int i = rep * 256 + tid;
        int bl = i >> 6, f = i & 63;
        float s = gcnb[f];
        const float* wr = wxl + bl * 176;
        #pragma unroll 13
        for (int l = 0; l < LL; ++l) s += wr[l] * gcnw[l * OG + f];
        Gl[i] = s;
    }
    __syncthreads();
    float* gout = gates + (size_t)bt0 * 192;
    #pragma unroll
    for (int rep = 0; rep < 6; ++rep) {
        int i = rep * 256 + tid;
        int bl = i / 192, q = i - bl * 192;
        const float* gr = Gl + bl * 64;
        float s = bias192[q];
        #pragma unroll 16
        for (int k = 0; k < OG; ++k) s += gr[k] * WtAll[k * 192 + q];
        gout[i] = s;
    }
}

// ---------------- sequential GRU scan over t: one block per batch row ----------------
__global__ __launch_bounds__(256) void k_scan(
        const float* __restrict__ gates,
        const float* __restrict__ Wr, const float* __restrict__ Wu, const float* __restrict__ Wc,
        float* __restrict__ out) {
    __shared__ float hl[OH], rhl[OH];
    int b = blockIdx.x;
    int tid = threadIdx.x;
    int f = tid >> 2, q = tid & 3;
    float wr[16], wu[16], wc[16];
    #pragma unroll
    for (int i = 0; i < 16; ++i) {
        int col = OG + q * 16 + i;
        wr[i] = Wr[f * (OG + OH) + col];
        wu[i] = Wu[f * (OG + OH) + col];
        wc[i] = Wc[f * (OG + OH) + col];
    }
    float h = 0.f;
    if (tid < OH) hl[tid] = 0.f;
    __syncthreads();
    for (int t = 0; t < SS; ++t) {
        const float* gp = gates + ((size_t)b * SS + t) * 192;
        float gr = gp[f];
        float gu = gp[64 + f];
        float gc = gp[128 + f];
        float rv = 0.f, uv = 0.f;
        #pragma unroll
        for (int i = 0; i < 16; ++i) {
            float hv = hl[q * 16 + i];
            rv += wr[i] * hv;
            uv += wu[i] * hv;
        }
        rv += __shfl_xor(rv, 1); rv += __shfl_xor(rv, 2);
        uv += __shfl_xor(uv, 1); uv += __shfl_xor(uv, 2);
        float r = 1.f / (1.f + __expf(-(rv + gr)));
        float u = 1.f / (1.f + __expf(-(uv + gu)));
        if (q == 0) rhl[f] = r * h;
        __syncthreads();
        float cv = 0.f;
        #pragma unroll
        for (int i = 0; i < 16; ++i) cv += wc[i] * rhl[q * 16 + i];
        cv += __shfl_xor(cv, 1); cv += __shfl_xor(cv, 2);
        float cc = tanhf(cv + gc);
        if (q == 0) {
            h = u * h + (1.f - u) * cc;
            hl[f] = h;
        }
        __syncthreads();
    }
    if (q == 0) out[b * OH + f] = h;
}

extern "C" void kernel_launch(void* const* d_in, const int* in_sizes, int n_in,
                              void* d_out, int out_size, void* d_ws, size_t ws_size,
                              hipStream_t stream) {
    const float* x    = (const float*)d_in[0];
    const float* adj  = (const float*)d_in[1];
    const float* dw1w = (const float*)d_in[2];
    const float* dw1b = (const float*)d_in[3];
    const float* pw1w = (const float*)d_in[4];
    const float* pw1b = (const float*)d_in[5];
    const float* dw2w = (const float*)d_in[6];
    const float* dw2b = (const float*)d_in[7];
    const float* pw2w = (const float*)d_in[8];
    const float* pw2b = (const float*)d_in[9];
    const float* dw3w = (const float*)d_in[10];
    const float* dw3b = (const float*)d_in[11];
    const float* pw3w = (const float*)d_in[12];
    const float* pw3b = (const float*)d_in[13];
    const float* gcnw = (const float*)d_in[14];
    const float* gcnb = (const float*)d_in[15];
    const float* Wrw  = (const float*)d_in[16];
    const float* Wrb  = (const float*)d_in[17];
    const float* Wuw  = (const float*)d_in[18];
    const float* Wub  = (const float*)d_in[19];
    const float* Wcw  = (const float*)d_in[20];
    const float* Wcb  = (const float*)d_in[21];
    const float* br   = (const float*)d_in[22];
    const float* bu   = (const float*)d_in[23];
    const float* bc   = (const float*)d_in[24];
    float* out = (float*)d_out;

    // workspace layout (bytes); gates reuses the wxb region? (kept disjoint: plenty of ws)
    char* ws = (char*)d_ws;
    unsigned short* Ftb = (unsigned short*)(ws + 0);        // 14336 B
    float* WtAll        = (float*)(ws + 14336);             // 49152 B
    float* bias192      = (float*)(ws + 63488);             // 768 B
    float* beff         = (float*)(ws + 64256);             // 4 B
    float* Bmg          = (float*)(ws + 64320);             // 11160 B
    float* wxb          = (float*)(ws + 76800);             // 7680*176*4 = 5406720 B
    float* gates        = (float*)(ws + 5483520);           // 7680*192*4 = 5898240 B
    (void)ws_size; (void)in_sizes; (void)n_in; (void)out_size;

    k_setup1<<<1, 1024, 0, stream>>>(dw1w, dw1b, pw1w, pw1b, dw2w, dw2b, pw2w, pw2b,
                                     dw3w, dw3b, pw3w, pw3b,
                                     Wrw, Wrb, br, Wuw, Wub, bu, Wcw, Wcb, bc,
                                     Bmg, WtAll, bias192, beff);
    k_setupF<<<64, 128, 0, stream>>>(Bmg, dw1w, Ftb);
    k_main<<<BB * SS, 256, 0, stream>>>(x, adj, Ftb, beff, wxb);
    k_gg<<<BB * SS / 8, 256, 0, stream>>>(wxb, gcnw, gcnb, WtAll, bias192, gates);
    k_scan<<<BB, 256, 0, stream>>>(gates, Wrw, Wuw, Wcw, out);
}